// Round 9
// baseline (102.209 us; speedup 1.0000x reference)
//
#include <hip/hip_runtime.h>

typedef __attribute__((ext_vector_type(8))) __bf16 bf16x8;
typedef __attribute__((ext_vector_type(4))) float f32x4;
typedef __attribute__((ext_vector_type(4))) int i32x4;

constexpr int Bn = 8192, Nn = 256, M1n = 128, M2n = 64, Mn = 192, ITERS = 30;
constexpr float TAUc = 0.05f, SIGc = 0.05f;

__device__ __forceinline__ ushort f2bf(float f) {
  unsigned u = __builtin_bit_cast(unsigned, f);
  u = (u + 0x7FFFu + ((u >> 16) & 1u)) >> 16;
  return (ushort)u;
}

// packed f32->bf16 (RNE), 2 values per instruction
__device__ __forceinline__ unsigned cvtpk(float lo, float hi) {
  unsigned r;
  asm("v_cvt_pk_bf16_f32 %0, %1, %2" : "=v"(r) : "v"(lo), "v"(hi));
  return r;
}

// Pin a fragment into AGPRs: volatile asm result, cannot be rematerialized.
__device__ __forceinline__ void pina(i32x4& v) { asm volatile("" : "+a"(v)); }

// SWAPPED builtin MFMA: A-operand = pinned A-matrix fragment, B-operand = the
// LDS-streamed x/y fragment. Lane(fr,kg) reg g = D[m/n = tile*16+kg*4+g][batch=fr].
__device__ __forceinline__ f32x4 mfma_swp(i32x4 afrag, bf16x8 b, f32x4 acc) {
  return __builtin_amdgcn_mfma_f32_16x16x32_bf16(
      __builtin_bit_cast(bf16x8, afrag), b, acc, 0, 0, 0);
}

// Build bf16 copies of A = [A1;A2] in both orientations:
// Arm[m][n] (192x256 row-major), AT[n][m] (256x192 row-major).
__global__ void prep_kernel(const float* __restrict__ A1, const float* __restrict__ A2,
                            ushort* __restrict__ Arm, ushort* __restrict__ AT) {
  int i = blockIdx.x * 256 + threadIdx.x;
  if (i >= Mn * Nn) return;
  int m = i / Nn, n = i % Nn;
  float v = (m < M1n) ? A1[m * Nn + n] : A2[(m - M1n) * Nn + n];
  ushort b = f2bf(v);
  Arm[m * Nn + n] = b;
  AT[n * Mn + m] = b;
}

// 4 waves per block, ONE 16-row band per block. grid = 512 -> 2 independent
// blocks co-resident per CU (decorrelated barriers), 2 waves/SIMD.
// Wave w: GEMM-1 m-tiles {3w..3w+2} (8 fx reads, 24 MFMA);
//         GEMM-3 n-tiles {4w..4w+3} (6 fy reads, 24 MFMA).
// 48 A-fragments pinned in AGPRs (192); x, y, sigma*z, c state in registers.
__global__ __launch_bounds__(256, 2) void pdhg_kernel(
    const float* __restrict__ x0, const float* __restrict__ y10,
    const float* __restrict__ y20, const float* __restrict__ z,
    const float* __restrict__ c, const ushort* __restrict__ Arm,
    const ushort* __restrict__ AT, float* __restrict__ out) {
  __shared__ __align__(16) ushort xb_lds[16][264];  // xbar band (bf16)
  __shared__ __align__(16) ushort y_lds[16][200];   // y band (bf16)

  const int lane = threadIdx.x & 63;
  const int w = threadIdx.x >> 6;     // wave 0..3
  const int fr = lane & 15;           // batch row within band (output col)
  const int kg = lane >> 4;           // k-group / output row-quad
  const int row0 = blockIdx.x * 16;   // this block's 16-row band
  const int rG = row0 + fr;           // this lane's batch row

  float x[4][4];        // [n-tile t][g]
  float cv[4][4];
  float ys[3][4], zs[3][4];

  // ---- init x state (dwordx4) + initial xbar into LDS (b64)
#pragma unroll
  for (int t = 0; t < 4; ++t) {
    const int n0 = (4 * w + t) * 16 + kg * 4;
    *reinterpret_cast<f32x4*>(cv[t]) = *reinterpret_cast<const f32x4*>(&c[n0]);
    f32x4 v = *reinterpret_cast<const f32x4*>(&x0[rG * Nn + n0]);
#pragma unroll
    for (int g = 0; g < 4; ++g) x[t][g] = v[g];
    uint2 p = make_uint2(cvtpk(v[0], v[1]), cvtpk(v[2], v[3]));
    *reinterpret_cast<uint2*>(&xb_lds[fr][n0]) = p;
  }
  // ---- init y, sigma*z state (dwordx4)
#pragma unroll
  for (int i = 0; i < 3; ++i) {
    const int mt = 3 * w + i;
    const int m0 = mt * 16 + kg * 4;
    f32x4 zv = *reinterpret_cast<const f32x4*>(&z[rG * Mn + m0]);
    f32x4 yv = (mt < 8) ? *reinterpret_cast<const f32x4*>(&y10[rG * M1n + m0])
                        : *reinterpret_cast<const f32x4*>(&y20[rG * M2n + (m0 - M1n)]);
#pragma unroll
    for (int g = 0; g < 4; ++g) { zs[i][g] = SIGc * zv[g]; ys[i][g] = yv[g]; }
  }

  // ---- preload loop-invariant A fragments into AGPRs (48 frags = 192 AGPR)
  i32x4 armF[3][8], atF[4][6];
#pragma unroll
  for (int i = 0; i < 3; ++i) {
    const int m = (3 * w + i) * 16 + fr;
#pragma unroll
    for (int kf = 0; kf < 8; ++kf) {
      armF[i][kf] = *reinterpret_cast<const i32x4*>(&Arm[m * Nn + kf * 32 + kg * 8]);
      pina(armF[i][kf]);
    }
  }
#pragma unroll
  for (int t = 0; t < 4; ++t) {
    const int n = (4 * w + t) * 16 + fr;
#pragma unroll
    for (int kf = 0; kf < 6; ++kf) {
      atF[t][kf] = *reinterpret_cast<const i32x4*>(&AT[n * Mn + kf * 32 + kg * 8]);
      pina(atF[t][kf]);
    }
  }

  __syncthreads();

  for (int it = 0; it < ITERS; ++it) {
    // ---- GEMM-1: S = xbar @ A^T; fx streamed (8 reads), 3 m-tile chains
    f32x4 a0 = {0.f, 0.f, 0.f, 0.f}, a1 = a0, a2 = a0;
#pragma unroll
    for (int kf = 0; kf < 8; ++kf) {
      bf16x8 fx = *reinterpret_cast<const bf16x8*>(&xb_lds[fr][kf * 32 + kg * 8]);
      a0 = mfma_swp(armF[0][kf], fx, a0);
      a1 = mfma_swp(armF[1][kf], fx, a1);
      a2 = mfma_swp(armF[2][kf], fx, a2);
    }

    // ---- y update; write bf16 Y (one ds_write_b64 per tile)
#pragma unroll
    for (int i = 0; i < 3; ++i) {
      const int mt = 3 * w + i;
      const int m0 = mt * 16 + kg * 4;
      const f32x4 ai = (i == 0) ? a0 : (i == 1) ? a1 : a2;
      const bool relu = (mt < 8);
#pragma unroll
      for (int g = 0; g < 4; ++g) {
        float s = __builtin_fmaf(SIGc, ai[g], ys[i][g]) - zs[i][g];
        ys[i][g] = relu ? fmaxf(s, 0.f) : s;
      }
      uint2 p = make_uint2(cvtpk(ys[i][0], ys[i][1]), cvtpk(ys[i][2], ys[i][3]));
      *reinterpret_cast<uint2*>(&y_lds[fr][m0]) = p;
    }
    __syncthreads();

    // ---- GEMM-3: G = y @ A; fy streamed (6 reads), 4 n-tile chains
    f32x4 q0 = {0.f, 0.f, 0.f, 0.f}, q1 = q0, q2 = q0, q3 = q0;
#pragma unroll
    for (int kf = 0; kf < 6; ++kf) {
      bf16x8 fy = *reinterpret_cast<const bf16x8*>(&y_lds[fr][kf * 32 + kg * 8]);
      q0 = mfma_swp(atF[0][kf], fy, q0);
      q1 = mfma_swp(atF[1][kf], fy, q1);
      q2 = mfma_swp(atF[2][kf], fy, q2);
      q3 = mfma_swp(atF[3][kf], fy, q3);
    }

    // ---- x update; write bf16 xbar (one ds_write_b64 per n-tile)
    const bool notlast = (it != ITERS - 1);
#pragma unroll
    for (int t = 0; t < 4; ++t) {
      const int n0 = (4 * w + t) * 16 + kg * 4;
      const f32x4 qt = (t == 0) ? q0 : (t == 1) ? q1 : (t == 2) ? q2 : q3;
      float xb[4];
#pragma unroll
      for (int g = 0; g < 4; ++g) {
        float grad = cv[t][g] + qt[g];
        float xn = fmaxf(__builtin_fmaf(-TAUc, grad, x[t][g]), 0.f);
        xb[g] = 2.f * xn - x[t][g];  // theta = 1
        x[t][g] = xn;
      }
      if (notlast) {
        uint2 p = make_uint2(cvtpk(xb[0], xb[1]), cvtpk(xb[2], xb[3]));
        *reinterpret_cast<uint2*>(&xb_lds[fr][n0]) = p;
      }
    }
    if (notlast) __syncthreads();
  }

  // ---- store outputs (all dwordx4): x (Bx256), y1 (Bx128), y2 (Bx64)
  float* ox = out;
  float* oy1 = out + Bn * Nn;
  float* oy2 = oy1 + Bn * M1n;
#pragma unroll
  for (int t = 0; t < 4; ++t) {
    const int n0 = (4 * w + t) * 16 + kg * 4;
    f32x4 v;
#pragma unroll
    for (int g = 0; g < 4; ++g) v[g] = x[t][g];
    *reinterpret_cast<f32x4*>(&ox[rG * Nn + n0]) = v;
  }
#pragma unroll
  for (int i = 0; i < 3; ++i) {
    const int mt = 3 * w + i;
    const int m0 = mt * 16 + kg * 4;
    f32x4 v;
#pragma unroll
    for (int g = 0; g < 4; ++g) v[g] = ys[i][g];
    if (mt < 8) *reinterpret_cast<f32x4*>(&oy1[rG * M1n + m0]) = v;
    else        *reinterpret_cast<f32x4*>(&oy2[rG * M2n + (m0 - M1n)]) = v;
  }
}

extern "C" void kernel_launch(void* const* d_in, const int* in_sizes, int n_in,
                              void* d_out, int out_size, void* d_ws, size_t ws_size,
                              hipStream_t stream) {
  const float* x0  = (const float*)d_in[0];
  const float* y10 = (const float*)d_in[1];
  const float* y20 = (const float*)d_in[2];
  const float* z   = (const float*)d_in[3];
  const float* c   = (const float*)d_in[4];
  const float* A1  = (const float*)d_in[5];
  const float* A2  = (const float*)d_in[6];

  ushort* Arm = (ushort*)d_ws;          // 192*256 bf16
  ushort* AT  = Arm + Mn * Nn;          // 256*192 bf16

  prep_kernel<<<(Mn * Nn + 255) / 256, 256, 0, stream>>>(A1, A2, Arm, AT);
  pdhg_kernel<<<Bn / 16, 256, 0, stream>>>(x0, y10, y20, z, c, Arm, AT, (float*)d_out);
}